// Round 2
// baseline (988.697 us; speedup 1.0000x reference)
//
#include <hip/hip_runtime.h>
#include <stdint.h>
#include <stddef.h>

// z = x[32768,512] @ W[2048,512]^T + B; per-row instance-norm over 2048;
// out = (z_norm + y) * y.  f32 I/O, bf16 MFMA GEMM internally.
//
// Persistent design: grid = 256 blocks (1 per CU), each block owns 128 rows
// processed as 4 generations of BM=32. Epilogue(g) flows into K-loop(g+1)
// with no intervening barrier; A is double-buffered and staged during the
// previous K-loop; stats LDS is parity-buffered.

typedef float f32x4_t __attribute__((ext_vector_type(4)));
typedef short short8_t __attribute__((ext_vector_type(8)));

#define BATCH   32768
#define INF     512
#define OUTF    2048
#define BM      32
#define GENS    4
#define ROWS_PER_BLK (BM * GENS)   // 128
#define NBLK    (BATCH / ROWS_PER_BLK)   // 256
#define THREADS 512
#define WB_BYTES (OUTF * INF * 2)  // 2 MB bf16 W

// LDS layout
#define A_OFF(p)   ((p) * 32768)               // 2 x 32 KB A tiles (bf16, k8-major)
#define ST_OFF(p)  (65536 + (p) * 2048)        // 2 x [8][32][2] f32 partial stats
#define RS_OFF(p)  (69632 + (p) * 256)         // 2 x [32][2] f32 (mean, rstd)
#define SMEM_BYTES 70144

__device__ __forceinline__ unsigned short f2bf(float f) {
    unsigned int u = __builtin_bit_cast(unsigned int, f);
    u += 0x7FFFu + ((u >> 16) & 1u);          // round-to-nearest-even
    return (unsigned short)(u >> 16);
}

__device__ __forceinline__ short8_t pack8(float4 a, float4 b) {
    short8_t v;
    v[0] = (short)f2bf(a.x); v[1] = (short)f2bf(a.y);
    v[2] = (short)f2bf(a.z); v[3] = (short)f2bf(a.w);
    v[4] = (short)f2bf(b.x); v[5] = (short)f2bf(b.y);
    v[6] = (short)f2bf(b.z); v[7] = (short)f2bf(b.w);
    return v;
}

// Prepass: W f32 [2048,512] -> Wb bf16 fragment-major: Wb[kk8][o][j] = W[o][kk8*8+j]
__global__ __launch_bounds__(256) void conv_w_kernel(const float* __restrict__ W,
                                                     unsigned short* __restrict__ Wb) {
    int id  = blockIdx.x * 256 + threadIdx.x;   // o*64 + kk8
    int o   = id >> 6;
    int kk8 = id & 63;
    const float* src = W + (size_t)o * INF + kk8 * 8;
    float4 a = *(const float4*)src;
    float4 b = *(const float4*)(src + 4);
    *(short8_t*)(Wb + (size_t)kk8 * (OUTF * 8) + o * 8) = pack8(a, b);
}

template <bool USE_WB>
__global__ __launch_bounds__(THREADS, 2) void fused_kernel(
    const float* __restrict__ x, const float* __restrict__ y,
    const float* __restrict__ W, const float* __restrict__ Bias,
    const unsigned short* __restrict__ Wb, float* __restrict__ out) {

    __shared__ __align__(16) char smem[SMEM_BYTES];

    const int t   = threadIdx.x;
    const int w   = t >> 6;
    const int l   = t & 63;
    const int l15 = l & 15;
    const int lg  = l >> 4;
    const int m_base = blockIdx.x * ROWS_PER_BLK;

    // bias fragment (persistent across gens)
    float biasv[16];
    #pragma unroll
    for (int ni = 0; ni < 16; ++ni)
        biasv[ni] = Bias[w * 256 + ni * 16 + l15];

    const unsigned short* wptr = nullptr;
    const float* wf = nullptr;
    if (USE_WB) wptr = Wb + ((size_t)lg << 14) + (size_t)(w * 256 + l15) * 8; // + s*65536 + ni*128
    else        wf   = W + (size_t)(w * 256 + l15) * INF + lg * 8;            // + ni*16*INF + s*32

    // ---- prologue: stage gen 0 into A[0] ----
    {
        char* Ab = smem + A_OFF(0);
        const float* xs = x + (size_t)(m_base + w) * INF + l * 8;
        #pragma unroll
        for (int i = 0; i < 4; ++i) {   // row = i*8 + w, k8 = l
            float4 a = *(const float4*)(xs + i * 8 * INF);
            float4 b = *(const float4*)(xs + i * 8 * INF + 4);
            *(short8_t*)(Ab + l * 512 + w * 16 + i * 128) = pack8(a, b);
        }
    }
    __syncthreads();

    for (int g = 0; g < GENS; ++g) {
        const int par = g & 1;
        const char* Acur = smem + A_OFF(par);
        char*       Anxt = smem + A_OFF(par ^ 1);
        float*      stats   = (float*)(smem + ST_OFF(par));
        float*      rowstat = (float*)(smem + RS_OFF(par));
        const bool  stage_next = (g + 1 < GENS);

        f32x4_t acc[2][16];
        #pragma unroll
        for (int mi = 0; mi < 2; ++mi)
            #pragma unroll
            for (int ni = 0; ni < 16; ++ni)
                acc[mi][ni] = (f32x4_t)(0.0f);

        // ---- early-issue next-gen x loads (land during this K-loop) ----
        float4 xa0, xb0, xa1, xb1, xa2, xb2, xa3, xb3;
        const float* xs = x + (size_t)(m_base + (g + 1) * BM + w) * INF + l * 8;
        if (stage_next) {
            xa0 = *(const float4*)(xs);                xb0 = *(const float4*)(xs + 4);
            xa1 = *(const float4*)(xs + 8 * INF);      xb1 = *(const float4*)(xs + 8 * INF + 4);
            xa2 = *(const float4*)(xs + 16 * INF);     xb2 = *(const float4*)(xs + 16 * INF + 4);
            xa3 = *(const float4*)(xs + 24 * INF);     xb3 = *(const float4*)(xs + 24 * INF + 4);
        }
        char* wdst = Anxt + l * 512 + w * 16;   // chunk i at +i*128

        const char* aptr = Acur + lg * 512 + l15 * 16;

        // ---- K loop: 16 steps of K=32; W streamed from L2; staging writes
        //      interleaved one chunk per 4 steps ----
        #pragma unroll
        for (int sc = 0; sc < 4; ++sc) {
            #pragma unroll
            for (int si = 0; si < 4; ++si) {
                const int s = sc * 4 + si;
                short8_t a0 = *(const short8_t*)(aptr + s * 2048);
                short8_t a1 = *(const short8_t*)(aptr + s * 2048 + 256);
                #pragma unroll
                for (int ni = 0; ni < 16; ++ni) {
                    short8_t bfr;
                    if (USE_WB) {
                        bfr = *(const short8_t*)(wptr + (size_t)s * 65536 + ni * 128);
                    } else {
                        const float* p = wf + (size_t)ni * 16 * INF + s * 32;
                        bfr = pack8(*(const float4*)p, *(const float4*)(p + 4));
                    }
                    acc[0][ni] = __builtin_amdgcn_mfma_f32_16x16x32_bf16(a0, bfr, acc[0][ni], 0, 0, 0);
                    acc[1][ni] = __builtin_amdgcn_mfma_f32_16x16x32_bf16(a1, bfr, acc[1][ni], 0, 0, 0);
                }
            }
            if (stage_next) {
                if (sc == 0) *(short8_t*)(wdst)       = pack8(xa0, xb0);
                if (sc == 1) *(short8_t*)(wdst + 128) = pack8(xa1, xb1);
                if (sc == 2) *(short8_t*)(wdst + 256) = pack8(xa2, xb2);
                if (sc == 3) *(short8_t*)(wdst + 384) = pack8(xa3, xb3);
            }
        }

        // ---- bias ----
        #pragma unroll
        for (int mi = 0; mi < 2; ++mi)
            #pragma unroll
            for (int ni = 0; ni < 16; ++ni)
                #pragma unroll
                for (int q = 0; q < 4; ++q)
                    acc[mi][ni][q] += biasv[ni];

        // ---- per-row partial stats: lane over 16 ni, 16-lane xor reduce ----
        #pragma unroll
        for (int mi = 0; mi < 2; ++mi) {
            #pragma unroll
            for (int q = 0; q < 4; ++q) {
                float s1 = 0.f, s2 = 0.f;
                #pragma unroll
                for (int ni = 0; ni < 16; ++ni) {
                    float v = acc[mi][ni][q];
                    s1 += v; s2 += v * v;
                }
                #pragma unroll
                for (int d = 1; d < 16; d <<= 1) {
                    s1 += __shfl_xor(s1, d);
                    s2 += __shfl_xor(s2, d);
                }
                if (l15 == 0) {
                    int r = mi * 16 + lg * 4 + q;
                    stats[(w * 32 + r) * 2]     = s1;
                    stats[(w * 32 + r) * 2 + 1] = s2;
                }
            }
        }
        __syncthreads();                       // stats in, A(g+1) staged

        if (t < 32) {
            float s1 = 0.f, s2 = 0.f;
            #pragma unroll
            for (int wi = 0; wi < 8; ++wi) {
                s1 += stats[(wi * 32 + t) * 2];
                s2 += stats[(wi * 32 + t) * 2 + 1];
            }
            float mean = s1 * (1.0f / OUTF);
            float var  = s2 * (1.0f / OUTF) - mean * mean;
            rowstat[t * 2]     = mean;
            rowstat[t * 2 + 1] = rsqrtf(var + 1e-5f);
        }
        __syncthreads();                       // rowstat ready

        // ---- epilogue: direct frag-layout stores (no LDS transpose, no
        //      trailing barrier -> flows into K(g+1)) ----
        const int m0 = m_base + g * BM;
        #pragma unroll
        for (int mi = 0; mi < 2; ++mi) {
            float mean[4], rstd[4];
            #pragma unroll
            for (int q = 0; q < 4; ++q) {
                int r = mi * 16 + lg * 4 + q;
                mean[q] = rowstat[r * 2];
                rstd[q] = rowstat[r * 2 + 1];
            }
            const size_t base = (size_t)(m0 + mi * 16 + lg * 4) * OUTF + w * 256 + l15;
            #pragma unroll
            for (int q = 0; q < 4; ++q) {
                #pragma unroll
                for (int ni = 0; ni < 16; ++ni) {
                    size_t off = base + (size_t)q * OUTF + ni * 16;
                    float yv = y[off];
                    float zn = (acc[mi][ni][q] - mean[q]) * rstd[q];
                    out[off] = (zn + yv) * yv;
                }
            }
        }
    }
}

extern "C" void kernel_launch(void* const* d_in, const int* in_sizes, int n_in,
                              void* d_out, int out_size, void* d_ws, size_t ws_size,
                              hipStream_t stream) {
    const float* x = (const float*)d_in[0];
    const float* y = (const float*)d_in[1];
    const float* W = (const float*)d_in[2];
    const float* B = (const float*)d_in[3];
    float* out = (float*)d_out;

    if (ws_size >= (size_t)WB_BYTES) {
        unsigned short* Wb = (unsigned short*)d_ws;
        conv_w_kernel<<<512, 256, 0, stream>>>(W, Wb);
        fused_kernel<true><<<NBLK, THREADS, 0, stream>>>(x, y, W, B, Wb, out);
    } else {
        fused_kernel<false><<<NBLK, THREADS, 0, stream>>>(x, y, W, B, nullptr, out);
    }
}